// Round 21
// baseline (416.125 us; speedup 1.0000x reference)
//
#include <hip/hip_runtime.h>
#include <math.h>

typedef unsigned short u16;
typedef __attribute__((ext_vector_type(8))) short short8;
typedef __attribute__((ext_vector_type(4))) float f32x4;

#define DI static __device__ __forceinline__

DI float bf2f(u16 u) { union { unsigned u; float f; } c; c.u = (unsigned)u << 16; return c.f; }
DI u16 f2bf(float f) {
  union { float f; unsigned u; } c; c.f = f;
  unsigned r = c.u + 0x7fffu + ((c.u >> 16) & 1u);
  return (u16)(r >> 16);
}

// async global->LDS, 16 bytes per lane; dest MUST be wave-linear (base + lane*16)
DI void gload16(const u16* g, u16* l) {
  __builtin_amdgcn_global_load_lds(
      (const __attribute__((address_space(1))) unsigned int*)g,
      (__attribute__((address_space(3))) unsigned int*)l, 16, 0, 0);
}

// bijective XCD-aware block swizzle (m204 form) -- fallback
DI void xcd_swz(int& bx, int& by, int gx, int gy) {
  int id = by * gx + bx;
  int n = gx * gy;
  int q = n >> 3, r = n & 7;
  int xcd = id & 7, k = id >> 3;
  int s = (xcd < r) ? (xcd * (q + 1) + k) : (r * (q + 1) + (xcd - r) * q + k);
  bx = s % gx;
  by = s / gx;
}

// rectangular XCD chunking (for gemm256 grids): each XCD owns an 8 x RH rect
// so its working set fits the 4MB per-XCD L2 (round-13: g1 FETCH 108->43MB).
DI void xcd_swz_rect(int& bx, int& by, int gx, int gy) {
  if ((gx & 7) == 0) {
    int RC = gx >> 3;
    if (RC <= 8 && (8 % RC) == 0) {
      int RR = 8 / RC;
      if ((gy % RR) == 0) {
        int id = by * gx + bx;
        int xcd = id & 7, k = id >> 3;
        int rc = xcd % RC, rr = xcd / RC;
        int RH = gy / RR;
        bx = rc * 8 + (k & 7);
        by = rr * RH + (k >> 3);
        return;
      }
    }
  }
  xcd_swz(bx, by, gx, gy);
}

// fragment read with XOR swizzle
DI const short8* fragp(const u16* unit, int row, int g4) {
  int off = row * 64 + g4 * 16;
  off ^= ((off >> 7) & 3) << 4;
  return (const short8*)((const char*)unit + off);
}

// ---------- merged weight prep: 10 transposes in one dispatch ----------
struct PrepDesc { const float* src; u16* dst; int K, N, nbx, boff, perm; };
struct PrepArgs { PrepDesc d[10]; };

__global__ __launch_bounds__(256) void prep_all(PrepArgs a) {
  int bid = blockIdx.x;
  int i = 0;
  while (i < 9 && bid >= a.d[i + 1].boff) i++;
  const PrepDesc D = a.d[i];
  int rel = bid - D.boff;
  int bx = rel % D.nbx, by = rel / D.nbx;
  int K = D.K, N = D.N;
  __shared__ float tile[32][33];
  int k0 = by * 32, n0 = bx * 32;
  int tid = threadIdx.x;
  int ni = tid & 31, ki8 = tid >> 5;
  for (int q = 0; q < 4; q++) {
    int k = ki8 + q * 8;
    tile[k][ni] = D.src[(size_t)(k0 + k) * N + n0 + ni];
  }
  __syncthreads();
  int kj = tid & 31, nj8 = tid >> 5;
  for (int q = 0; q < 4; q++) {
    int n = nj8 + q * 8;
    int nold = n0 + n;
    int rowp = nold;
    if (D.perm) {
      rowp = (nold < 2560) ? ((nold >> 5) * 64 + (nold & 31))
                           : (((nold - 2560) >> 5) * 64 + 32 + (nold & 31));
    }
    D.dst[(size_t)rowp * K + k0 + kj] = f2bf(tile[kj][n]);
  }
}

// ---------- misc prep: prompt f32->bf16 (0..1231) + bias concat (1232..1236)
//            + GroupNorm stats (1237..1492) ----------
__global__ __launch_bounds__(256) void misc_prep(const float* __restrict__ p,
                                                 u16* __restrict__ pbf,
                                                 const float* __restrict__ ka,
                                                 const float* __restrict__ va,
                                                 float* __restrict__ cbias,
                                                 const float* __restrict__ x,
                                                 float* __restrict__ mean_o,
                                                 float* __restrict__ rstd_o) {
  int bid = blockIdx.x;
  if (bid < 1232) {
    long i = (long)bid * 256 + threadIdx.x;
    if (i < (long)616 * 512) pbf[i] = f2bf(p[i]);
  } else if (bid < 1237) {
    int i = (bid - 1232) * 256 + threadIdx.x;
    if (i < 640) cbias[i] = ka[i];
    else if (i < 1280) cbias[i] = va[i - 640];
  } else {
    int bg = bid - 1237;
    const float4* p4 = (const float4*)(x + (size_t)bg * 20480);
    float s = 0.f, sq = 0.f;
    for (int i = threadIdx.x; i < 5120; i += 256) {
      float4 v = p4[i];
      s += v.x + v.y + v.z + v.w;
      sq += v.x * v.x + v.y * v.y + v.z * v.z + v.w * v.w;
    }
    for (int off = 1; off < 64; off <<= 1) { s += __shfl_xor(s, off); sq += __shfl_xor(sq, off); }
    __shared__ float ps[4], pq[4];
    int w = threadIdx.x >> 6;
    if ((threadIdx.x & 63) == 0) { ps[w] = s; pq[w] = sq; }
    __syncthreads();
    if (threadIdx.x == 0) {
      float S = ps[0] + ps[1] + ps[2] + ps[3];
      float Q = pq[0] + pq[1] + pq[2] + pq[3];
      float mu = S / 20480.f;
      float var = Q / 20480.f - mu * mu;
      mean_o[bg] = mu;
      rstd_o[bg] = rsqrtf(var + 1e-5f);
    }
  }
}

// ---------- GN apply + transpose ----------
__global__ __launch_bounds__(256) void gn_apply(const float* __restrict__ x,
                                                const float* __restrict__ mean_,
                                                const float* __restrict__ rstd_,
                                                const float* __restrict__ g,
                                                const float* __restrict__ bb,
                                                u16* __restrict__ out) {
  __shared__ float tile[32][33];
  int b = blockIdx.z, c0 = blockIdx.y * 32, s0 = blockIdx.x * 32;
  int tid = threadIdx.x;
  int si = tid & 31, ci8 = tid >> 5;
  for (int i = 0; i < 4; i++) {
    int c = c0 + ci8 + i * 8;
    int gg = c / 20;
    float mu = mean_[b * 32 + gg], rs = rstd_[b * 32 + gg];
    float v = x[((size_t)b * 640 + c) * 1024 + s0 + si];
    tile[ci8 + i * 8][si] = (v - mu) * rs * g[c] + bb[c];
  }
  __syncthreads();
  int cj = tid & 31, sj8 = tid >> 5;
  for (int i = 0; i < 4; i++) {
    int sj = sj8 + i * 8;
    out[((size_t)b * 1024 + s0 + sj) * 640 + c0 + cj] = f2bf(tile[cj][sj]);
  }
}

// ---------- LayerNorm: bf16 [T,640] -> bf16 [T,640], vectorized short8 loads ----------
__global__ __launch_bounds__(256) void ln_kernel(const u16* __restrict__ in,
                                                 const float* __restrict__ g,
                                                 const float* __restrict__ bb,
                                                 u16* __restrict__ out) {
  int t = blockIdx.x * 4 + (threadIdx.x >> 6);
  int lane = threadIdx.x & 63;
  const u16* row = in + (size_t)t * 640;
  const bool tail = (lane < 16);
  short8 v0 = *(const short8*)(row + lane * 8);
  short8 v1 = tail ? *(const short8*)(row + 512 + lane * 8) : short8{0,0,0,0,0,0,0,0};
  float f0[8], f1[8];
  float s = 0.f, sq = 0.f;
#pragma unroll
  for (int e = 0; e < 8; e++) {
    f0[e] = bf2f((u16)v0[e]);
    s += f0[e];
    sq += f0[e] * f0[e];
  }
  if (tail) {
#pragma unroll
    for (int e = 0; e < 8; e++) {
      f1[e] = bf2f((u16)v1[e]);
      s += f1[e];
      sq += f1[e] * f1[e];
    }
  }
#pragma unroll
  for (int off = 1; off < 64; off <<= 1) { s += __shfl_xor(s, off); sq += __shfl_xor(sq, off); }
  float mu = s * (1.f / 640.f);
  float var = sq * (1.f / 640.f) - mu * mu;
  float rstd = rsqrtf(var + 1e-5f);
  short8 o0;
#pragma unroll
  for (int e = 0; e < 8; e++) {
    int c = lane * 8 + e;
    o0[e] = (short)f2bf((f0[e] - mu) * rstd * g[c] + bb[c]);
  }
  *(short8*)(out + (size_t)t * 640 + lane * 8) = o0;
  if (tail) {
    short8 o1;
#pragma unroll
    for (int e = 0; e < 8; e++) {
      int c = 512 + lane * 8 + e;
      o1[e] = (short)f2bf((f1[e] - mu) * rstd * g[c] + bb[c]);
    }
    *(short8*)(out + (size_t)t * 640 + 512 + lane * 8) = o1;
  }
}

// ---------- epilogue helper ----------
// MODE 1: bf16 = acc+bias    MODE 6: bf16 = acc+bias+bf16res
template <int MODE>
DI void store_elem(void* outp, const float* res, size_t o, float val) {
  if (MODE == 1)
    ((u16*)outp)[o] = f2bf(val);
  else if (MODE == 6)
    ((u16*)outp)[o] = f2bf(val + bf2f(((const u16*)res)[o]));
}

// ================= 256x256 fine-phased GEMM (g1, qkv) =================
template <int MODE>
__global__ __launch_bounds__(512, 1) void gemm256(const u16* __restrict__ A,
                                                  const u16* __restrict__ Bt,
                                                  const float* __restrict__ bias,
                                                  void* outp, const float* res,
                                                  int M, int N, int K) {
  __shared__ __align__(16) u16 As[4][8192];
  __shared__ __align__(16) u16 Bs[4][8192];
  const int tid = threadIdx.x;
  const int lane = tid & 63, wid = tid >> 6;
  const int wm = wid >> 2, wn = wid & 3;
  const int rq = lane & 15, g4 = lane >> 4;
  int bx = blockIdx.x, by = blockIdx.y;
  xcd_swz_rect(bx, by, gridDim.x, gridDim.y);
  const int m0 = bx * 256, n0 = by * 256;

  int D0 = tid * 16;
  int so = D0 ^ (((D0 >> 7) & 3) << 4);
  const int srow = so >> 6;
  const int sk16 = (so & 63) >> 1;

  f32x4 acc[8][4] = {};
  const int nt = K >> 5;

#define STG_A(kt)                                                              \
  {                                                                            \
    gload16(A + (size_t)(m0 + srow) * K + (kt)*32 + sk16,                      \
            &As[(kt) & 3][0] + tid * 8);                                       \
    gload16(A + (size_t)(m0 + 128 + srow) * K + (kt)*32 + sk16,                \
            &As[(kt) & 3][4096] + tid * 8);                                    \
  }
#define STG_B(kt)                                                              \
  {                                                                            \
    gload16(Bt + (size_t)(n0 + srow) * K + (kt)*32 + sk16,                     \
            &Bs[(kt) & 3][0] + tid * 8);                                       \
    gload16(Bt + (size_t)(n0 + 128 + srow) * K + (kt)*32 + sk16,               \
            &Bs[(kt) & 3][4096] + tid * 8);                                    \
  }
#define BAR asm volatile("s_barrier" ::: "memory")

#define PH1(T)                                                                 \
  {                                                                            \
    const u16* Au = &As[(T) & 3][0];                                           \
    const u16* Bu = &Bs[(T) & 3][0];                                           \
    _Pragma("unroll") for (int i = 0; i < 4; i++)                              \
        af[i] = *fragp(Au, wm * 128 + i * 16 + rq, g4);                        \
    _Pragma("unroll") for (int j = 0; j < 4; j++)                              \
        bf[j] = *fragp(Bu, wn * 64 + j * 16 + rq, g4);                         \
    BAR;                                                                       \
    asm volatile("s_waitcnt lgkmcnt(0)" ::: "memory");                         \
    __builtin_amdgcn_sched_barrier(0);                                         \
    __builtin_amdgcn_s_setprio(1);                                             \
    _Pragma("unroll") for (int i = 0; i < 4; i++)                              \
        _Pragma("unroll") for (int j = 0; j < 4; j++)                          \
            acc[i][j] =                                                        \
        __builtin_amdgcn_mfma_f32_16x16x32_bf16(af[i], bf[j], acc[i][j], 0, 0, 0); \
    __builtin_amdgcn_s_setprio(0);                                             \
  }

#define PH2(T, DO_STG, WSTR)                                                   \
  {                                                                            \
    const u16* Au = &As[(T) & 3][0];                                           \
    _Pragma("unroll") for (int i = 0; i < 4; i++)                              \
        af[i] = *fragp(Au, wm * 128 + 64 + i * 16 + rq, g4);                   \
    if (DO_STG) { STG_A((T) + 3); STG_B((T) + 3); }                            \
    asm volatile(WSTR ::: "memory");                                           \
    BAR;                                                                       \
    asm volatile("s_waitcnt lgkmcnt(0)" ::: "memory");                         \
    __builtin_amdgcn_sched_barrier(0);                                         \
    __builtin_amdgcn_s_setprio(1);                                             \
    _Pragma("unroll") for (int i = 0; i < 4; i++)                              \
        _Pragma("unroll") for (int j = 0; j < 4; j++)                          \
            acc[4 + i][j] =                                                    \
        __builtin_amdgcn_mfma_f32_16x16x32_bf16(af[i], bf[j], acc[4 + i][j], 0, 0, 0); \
    __builtin_amdgcn_s_setprio(0);                                             \
  }

  STG_A(0); STG_B(0); STG_A(1); STG_B(1); STG_A(2); STG_B(2);
  asm volatile("s_waitcnt vmcnt(8)" ::: "memory");
  BAR;

  short8 af[4], bf[4];
  int t = 0;
  for (; t < nt - 3; t++) {
    PH1(t);
    PH2(t, true, "s_waitcnt vmcnt(8)");
  }
  PH1(t); PH2(t, false, "s_waitcnt vmcnt(4)"); t++;
  PH1(t); PH2(t, false, "s_waitcnt vmcnt(0)"); t++;
  PH1(t); PH2(t, false, "s_nop 0");

  if (MODE == 5) {
#pragma unroll
    for (int mf = 0; mf < 8; mf++) {
      int mb = m0 + wm * 128 + mf * 16 + g4 * 4;
#pragma unroll
      for (int j = 0; j < 2; j++) {
        int n = n0 + wn * 64 + j * 16 + rq;  // (n&63) < 32
        int c = (n >> 6) * 32 + (n & 31);
        float ba = bias[c];
        float bg = bias[2560 + c];
#pragma unroll
        for (int r = 0; r < 4; r++) {
          float a = acc[mf][j][r] + ba;
          float gt = acc[mf][j + 2][r] + bg;
          float gl = 0.5f * gt * (1.f + erff(gt * 0.70710678f));
          ((u16*)outp)[(size_t)(mb + r) * 2560 + c] = f2bf(a * gl);
        }
      }
    }
  } else {
#pragma unroll
    for (int mf = 0; mf < 8; mf++) {
#pragma unroll
      for (int j = 0; j < 4; j++) {
        int n = n0 + wn * 64 + j * 16 + rq;
        if (n >= N) continue;
        float bv = bias[n];
        int mb = m0 + wm * 128 + mf * 16 + g4 * 4;
        f32x4 v = acc[mf][j];
#pragma unroll
        for (int r = 0; r < 4; r++) {
          size_t o = (size_t)(mb + r) * N + n;
          ((u16*)outp)[o] = f2bf(v[r] + bv);
        }
      }
    }
  }
  (void)res;
#undef STG_A
#undef STG_B
#undef PH1
#undef PH2
#undef BAR
}

// ========= 64x128 GEMM body (shared by single & dual kernels) =========
// MODE 1: bf16  MODE 3: NCHW fp32 + x residual  MODE 6: bf16 = acc+bias+bf16res
template <int MODE>
DI void gemm64_body(u16* AsB, u16* BsB,
                    const u16* __restrict__ A, const u16* __restrict__ Bt,
                    const float* __restrict__ bias, void* outp, const float* res,
                    int M, int N, int K, int bx, int by, int gx, int gy) {
  const int tid = threadIdx.x;
  const int lane = tid & 63, wid = tid >> 6;
  const int wm = wid >> 1, wn = wid & 1;
  xcd_swz(bx, by, gx, gy);
  const int m0 = bx * 64, n0 = by * 128;
  const int rq = lane & 15, g4 = lane >> 4;

  int D0 = tid * 16;
  int so = D0 ^ (((D0 >> 7) & 3) << 4);
  const int srowS = so >> 6;
  const int sk16 = (so & 63) >> 1;
  int gmA = m0 + srowS;  if (gmA >= M) gmA = M - 1;
  const u16* gA = A + (size_t)gmA * K + sk16;
  const u16* gB0 = Bt + (size_t)(n0 + srowS) * K + sk16;
  const u16* gB1 = Bt + (size_t)(n0 + 64 + srowS) * K + sk16;

  f32x4 acc[2][4] = {};

  auto STAGE = [&](int buf, int k0) {
    gload16(gA + k0, AsB + buf * 2048 + tid * 8);
    gload16(gB0 + k0, BsB + buf * 4096 + tid * 8);
    gload16(gB1 + k0, BsB + buf * 4096 + 2048 + tid * 8);
  };
  auto COMPUTE = [&](int buf) {
    short8 af[2], bfr[4];
    for (int i = 0; i < 2; i++)
      af[i] = *fragp(AsB + buf * 2048, wm * 32 + i * 16 + rq, g4);
    for (int j = 0; j < 4; j++)
      bfr[j] = *fragp(BsB + buf * 4096, wn * 64 + j * 16 + rq, g4);
    __builtin_amdgcn_s_setprio(1);
    for (int i = 0; i < 2; i++)
      for (int j = 0; j < 4; j++)
        acc[i][j] = __builtin_amdgcn_mfma_f32_16x16x32_bf16(af[i], bfr[j], acc[i][j], 0, 0, 0);
    __builtin_amdgcn_s_setprio(0);
  };

  const int nk = K >> 5;
  STAGE(0, 0);
  STAGE(1, 32);
  int t = 0;
  for (; t < nk - 2; t++) {
    STAGE((t + 2) & 3, (t + 2) << 5);
    asm volatile("s_waitcnt vmcnt(6)" ::: "memory");
    __builtin_amdgcn_s_barrier();
    COMPUTE(t & 3);
  }
  asm volatile("s_waitcnt vmcnt(3)" ::: "memory");
  __builtin_amdgcn_s_barrier();
  COMPUTE(t & 3);
  t++;
  asm volatile("s_waitcnt vmcnt(0)" ::: "memory");
  __builtin_amdgcn_s_barrier();
  COMPUTE(t & 3);

  for (int j = 0; j < 4; j++) {
    int n = n0 + wn * 64 + j * 16 + rq;
    float bv = bias[n];
    for (int i = 0; i < 2; i++) {
      int mb = m0 + wm * 32 + i * 16 + g4 * 4;
      f32x4 v = acc[i][j];
      if (MODE == 3) {
        int b = mb >> 10, sp = mb & 1023;
        size_t o = ((size_t)b * 640 + n) * 1024 + sp;
        f32x4 xv = *(const f32x4*)(res + o);
        f32x4 ov;
        for (int r = 0; r < 4; r++) ov[r] = v[r] + bv + xv[r];
        *(f32x4*)((float*)outp + o) = ov;
      } else {
        for (int r = 0; r < 4; r++) {
          int m = mb + r;
          if (m >= M) break;
          store_elem<MODE>(outp, res, (size_t)m * N + n, v[r] + bv);
        }
      }
    }
  }
}

template <int MODE>
__global__ __launch_bounds__(256) void gemm_bt64(const u16* __restrict__ A,
                                                 const u16* __restrict__ Bt,
                                                 const float* __restrict__ bias,
                                                 void* outp, const float* res,
                                                 int M, int N, int K) {
  __shared__ __align__(16) u16 As[4 * 2048];
  __shared__ __align__(16) u16 Bs[4 * 4096];
  gemm64_body<MODE>(As, Bs, A, Bt, bias, outp, res, M, N, K,
                    blockIdx.x, blockIdx.y, gridDim.x, gridDim.y);
}

// dual-problem launch: blocks [0, nb1) run problem 1, rest run problem 2.
template <int MODE1, int MODE2>
__global__ __launch_bounds__(256) void gemm_bt64_dual(
    const u16* A1, const u16* Bt1, const float* b1, void* o1, int M1, int N1, int K1, int gx1, int gy1,
    const u16* A2, const u16* Bt2, const float* b2, void* o2, int M2, int N2, int K2, int gx2, int gy2,
    int nb1) {
  __shared__ __align__(16) u16 As[4 * 2048];
  __shared__ __align__(16) u16 Bs[4 * 4096];
  int id = blockIdx.x;
  if (id < nb1) {
    gemm64_body<MODE1>(As, Bs, A1, Bt1, b1, o1, nullptr, M1, N1, K1,
                       id % gx1, id / gx1, gx1, gy1);
  } else {
    id -= nb1;
    gemm64_body<MODE2>(As, Bs, A2, Bt2, b2, o2, nullptr, M2, N2, K2,
                       id % gx2, id / gx2, gx2, gy2);
  }
}

// ---------- flash attention: swapped QK^T, in-lane softmax, 16 q/wave, 8 waves ----------
// K AND V tiles prefetched into registers one iteration ahead (T14 async-STAGE
// split): loads issued right after the staging barrier land under compute.
__global__ __launch_bounds__(512) void attn_kernel(const u16* __restrict__ Qb, int ldq, long qbs,
                                                   const u16* __restrict__ Kb, int ldk, long kbs,
                                                   const u16* __restrict__ Vb,
                                                   u16* __restrict__ Ob, int ldo, long obs,
                                                   int Sk, float scale) {
  __shared__ __align__(16) u16 Ks[64 * 96];
  __shared__ __align__(16) u16 Vt[80 * 64];
  __shared__ __align__(16) u16 Ps[8][16 * 72];
  const short8 zero = {0, 0, 0, 0, 0, 0, 0, 0};
  const int tid = threadIdx.x;
  const int lane = tid & 63, w = tid >> 6;
  const int rq = lane & 15, g4 = lane >> 4;
  const int b = blockIdx.z, h = blockIdx.y;
  const u16* Q = Qb + (size_t)b * qbs + h * 80;
  const u16* Kp = Kb + (size_t)b * kbs + h * 80;
  const u16* Vp = Vb + (size_t)b * kbs + h * 80;
  u16* Op = Ob + (size_t)b * obs + h * 80;
  const int q0 = blockIdx.x * 128 + w * 16;
  const float Af = scale * 1.44269504f;

  short8 qa[3];
#pragma unroll
  for (int kk = 0; kk < 3; kk++) {
    int d = kk * 32 + g4 * 8;
    qa[kk] = (d < 80) ? *(const short8*)(Q + (size_t)(q0 + rq) * ldq + d) : zero;
  }
  f32x4 oacc[5] = {};
  float m_run = -1e30f, l_run = 0.f;

  // K-prefetch registers: chunk s=tid (row=s/12,c=s%12) and s=tid+512 (tid<256)
  const int r0 = tid / 12, c0_ = tid % 12;
  const int s1 = tid + 512;
  const int r1 = s1 / 12, c1_ = s1 % 12;
  short8 kr0, kr1;
  auto LOADK = [&](int kt) {
    int kb0 = kt * 64 + r0;
    kr0 = (c0_ < 10 && kb0 < Sk) ? *(const short8*)(Kp + (size_t)kb0 * ldk + c0_ * 8) : zero;
    if (tid < 256) {
      int kb1 = kt * 64 + r1;
      kr1 = (c1_ < 10 && kb1 < Sk) ? *(const short8*)(Kp + (size_t)kb1 * ldk + c1_ * 8) : zero;
    }
  };
  auto WRITEK = [&]() {
    int byte0 = r0 * 192 + c0_ * 16;
    byte0 ^= (r0 & 7) << 4;
    *(short8*)((char*)Ks + byte0) = kr0;
    if (tid < 256) {
      int byte1 = r1 * 192 + c1_ * 16;
      byte1 ^= (r1 & 7) << 4;
      *(short8*)((char*)Ks + byte1) = kr1;
    }
  };
  // V-prefetch registers: tid<320 owns (k2=(tid&31)*2, c=tid>>5)
  const int vk2 = (tid & 31) * 2, vc = tid >> 5;
  short8 vr0, vr1;
  auto LOADV = [&](int kt) {
    if (tid < 320) {
      int k0i = kt * 64 + vk2;
      vr0 = (k0i < Sk) ? *(const short8*)(Vp + (size_t)k0i * ldk + vc * 8) : zero;
      vr1 = (k0i + 1 < Sk) ? *(const short8*)(Vp + (size_t)(k0i + 1) * ldk + vc * 8) : zero;
    }
  };
  auto WRITEV = [&]() {
    if (tid < 320) {
#pragma unroll
      for (int jj = 0; jj < 8; jj++) {
        int d = vc * 8 + jj;
        unsigned cm = (unsigned)(u16)vr0[jj] | ((unsigned)(u16)vr1[jj] << 16);
        int byte = d * 128 + vk2 * 2;
        byte ^= (d & 7) << 4;
        *(unsigned*)((char*)Vt + byte) = cm;
      }
    }
  };

  const int nkt = (Sk + 63) >> 6;
  LOADK(0);
  LOADV(0);
  for (int kt = 0; kt < nkt; kt++) {
    const int kbase = kt * 64;
    WRITEK();  // compiler waits on kr/vr loads here
    WRITEV();
    __syncthreads();
    if (kt + 1 < nkt) { LOADK(kt + 1); LOADV(kt + 1); }  // lands under compute

    f32x4 sc[4] = {};
#pragma unroll
    for (int n = 0; n < 4; n++)
#pragma unroll
      for (int kk = 0; kk < 3; kk++) {
        int row = n * 16 + rq;
        int byte = row * 192 + (kk * 32 + g4 * 8) * 2;
        byte ^= (rq & 7) << 4;
        short8 kb = *(const short8*)((const char*)Ks + byte);
        sc[n] = __builtin_amdgcn_mfma_f32_16x16x32_bf16(kb, qa[kk], sc[n], 0, 0, 0);
      }
    const bool full = (kbase + 64 <= Sk);
    if (!full) {
#pragma unroll
      for (int n = 0; n < 4; n++)
#pragma unroll
        for (int r = 0; r < 4; r++)
          if (kbase + n * 16 + g4 * 4 + r >= Sk) sc[n][r] = -1e30f;
    }
    float t0 = fmaxf(fmaxf(sc[0][0], sc[0][1]), fmaxf(sc[0][2], sc[0][3]));
    float t1 = fmaxf(fmaxf(sc[1][0], sc[1][1]), fmaxf(sc[1][2], sc[1][3]));
    float t2 = fmaxf(fmaxf(sc[2][0], sc[2][1]), fmaxf(sc[2][2], sc[2][3]));
    float t3 = fmaxf(fmaxf(sc[3][0], sc[3][1]), fmaxf(sc[3][2], sc[3][3]));
    float tm = fmaxf(fmaxf(t0, t1), fmaxf(t2, t3));
    tm = fmaxf(tm, __shfl_xor(tm, 16));
    tm = fmaxf(tm, __shfl_xor(tm, 32));
    if (!__all(tm <= m_run + 48.0f)) {
      float mn = fmaxf(m_run, tm);
      float sf = exp2f(Af * (m_run - mn));
      m_run = mn;
      l_run *= sf;
      float sfo[4];
#pragma unroll
      for (int r = 0; r < 4; r++) sfo[r] = __shfl(sf, g4 * 4 + r);
#pragma unroll
      for (int nn = 0; nn < 5; nn++)
#pragma unroll
        for (int r = 0; r < 4; r++) oacc[nn][r] *= sfo[r];
    }
    const float Am = Af * m_run;
    float rs0 = 0.f, rs1 = 0.f;
#pragma unroll
    for (int n = 0; n < 4; n++) {
      float p0 = exp2f(fmaf(Af, sc[n][0], -Am));
      float p1 = exp2f(fmaf(Af, sc[n][1], -Am));
      float p2 = exp2f(fmaf(Af, sc[n][2], -Am));
      float p3 = exp2f(fmaf(Af, sc[n][3], -Am));
      sc[n][0] = p0; sc[n][1] = p1; sc[n][2] = p2; sc[n][3] = p3;
      rs0 += p0 + p1;
      rs1 += p2 + p3;
    }
    float rsum = rs0 + rs1;
    rsum += __shfl_xor(rsum, 16);
    rsum += __shfl_xor(rsum, 32);
    l_run += rsum;
#pragma unroll
    for (int n = 0; n < 4; n++) {
      unsigned pk0, pk1;
      asm("v_cvt_pk_bf16_f32 %0, %1, %2" : "=v"(pk0) : "v"(sc[n][0]), "v"(sc[n][1]));
      asm("v_cvt_pk_bf16_f32 %0, %1, %2" : "=v"(pk1) : "v"(sc[n][2]), "v"(sc[n][3]));
      int base = rq * 72 + n * 16 + g4 * 4;
      *(unsigned*)&Ps[w][base] = pk0;
      *(unsigned*)&Ps[w][base + 2] = pk1;
    }
    __builtin_amdgcn_s_setprio(1);
#pragma unroll
    for (int s = 0; s < 2; s++) {
      short8 pa = *(const short8*)&Ps[w][rq * 72 + s * 32 + g4 * 8];
#pragma unroll
      for (int nn = 0; nn < 5; nn++) {
        int row = nn * 16 + rq;
        int byte = row * 128 + (s * 32 + g4 * 8) * 2;
        byte ^= (rq & 7) << 4;
        short8 vb = *(const short8*)((const char*)Vt + byte);
        oacc[nn] = __builtin_amdgcn_mfma_f32_16x16x32_bf16(pa, vb, oacc[nn], 0, 0, 0);
      }
    }
    __builtin_amdgcn_s_setprio(0);
    __syncthreads();
  }
  float lo[4];
#pragma unroll
  for (int r = 0; r < 4; r++) lo[r] = 1.0f / __shfl(l_run, g4 * 4 + r);
#pragma unroll
  for (int nn = 0; nn < 5; nn++)
#pragma unroll
    for (int r = 0; r < 4; r++)
      Op[(size_t)(q0 + g4 * 4 + r) * ldo + nn * 16 + rq] = f2bf(oacc[nn][r] * lo[r]);
}

extern "C" void kernel_launch(void* const* d_in, const int* in_sizes, int n_in,
                              void* d_out, int out_size, void* d_ws, size_t ws_size,
                              hipStream_t stream) {
  (void)in_sizes; (void)n_in; (void)out_size; (void)ws_size;
  const float* x = (const float*)d_in[0];
  const float* p = (const float*)d_in[1];
  const float* gn_g = (const float*)d_in[2];
  const float* gn_b = (const float*)d_in[3];
  const float* ci_w = (const float*)d_in[4];
  const float* ci_b = (const float*)d_in[5];
  const float* ln1_g = (const float*)d_in[6];
  const float* ln1_b = (const float*)d_in[7];
  const float* qkv_w = (const float*)d_in[8];
  const float* qkv_b = (const float*)d_in[9];
  const float* saw_w = (const float*)d_in[10];
  const float* saw_b = (const float*)d_in[11];
  const float* ln2_g = (const float*)d_in[12];
  const float* ln2_b = (const float*)d_in[13];
  const float* caq_w = (const float*)d_in[14];
  const float* caq_b = (const float*)d_in[15];
  const float* cak_w = (const float*)d_in[16];
  const float* cak_b = (const float*)d_in[17];
  const float* cav_w = (const float*)d_in[18];
  const float* cav_b = (const float*)d_in[19];
  const float* caw_w = (const float*)d_in[20];
  const float* caw_b = (const float*)d_in[21];
  const float* ln3_g = (const float*)d_in[22];
  const float* ln3_b = (const float*)d_in[23];
  const float* g1_w = (const float*)d_in[24];
  const float* g1_b = (const float*)d_in[25];
  const float* g2_w = (const float*)d_in[26];
  const float* g2_b = (const float*)d_in[27];
  const float* co_w = (const float*)d_in[28];
  const float* co_b = (const float*)d_in[29];
  float* out = (float*)d_out;

  char* ws = (char*)d_ws;
  size_t off = 0;
  auto alloc = [&](size_t bytes) {
    size_t o = off;
    off += (bytes + 255) & ~(size_t)255;
    return o;
  };
  u16* WCI = (u16*)(ws + alloc((size_t)768 * 640 * 2));
  u16* WQKV = (u16*)(ws + alloc((size_t)2048 * 640 * 2));
  u16* WSAW = (u16*)(ws + alloc((size_t)768 * 640 * 2));
  u16* WCAQ = (u16*)(ws + alloc((size_t)768 * 640 * 2));
  u16* WCAKV = (u16*)(ws + alloc((size_t)1280 * 512 * 2));
  u16* WCAW = (u16*)(ws + alloc((size_t)768 * 640 * 2));
  u16* WG1 = (u16*)(ws + alloc((size_t)5120 * 640 * 2));
  u16* WG2 = (u16*)(ws + alloc((size_t)768 * 2560 * 2));
  u16* WCO = (u16*)(ws + alloc((size_t)768 * 640 * 2));
  u16* X = (u16*)(ws + alloc((size_t)8192 * 640 * 2));
  u16* Y = (u16*)(ws + alloc((size_t)8192 * 640 * 2));
  u16* F1B = (u16*)(ws + alloc((size_t)8192 * 640 * 2));  // bf16 residual stream
  u16* QKV = (u16*)(ws + alloc((size_t)8192 * 1920 * 2));
  u16* PBF = (u16*)(ws + alloc((size_t)616 * 512 * 2));
  u16* KVC = (u16*)(ws + alloc((size_t)616 * 1280 * 2));
  u16* TG = (u16*)(ws + alloc((size_t)8192 * 2560 * 2));
  float* GNM = (float*)(ws + alloc(256 * 4));
  float* GNR = (float*)(ws + alloc(256 * 4));
  float* CBIAS = (float*)(ws + alloc(1280 * 4));

  // ---- merged weight prep ----
  PrepArgs pa;
  int boff = 0;
  auto addw = [&](int idx, const float* src, u16* dst, int K, int N, int perm) {
    pa.d[idx].src = src; pa.d[idx].dst = dst;
    pa.d[idx].K = K; pa.d[idx].N = N;
    pa.d[idx].nbx = N / 32; pa.d[idx].boff = boff; pa.d[idx].perm = perm;
    boff += (N / 32) * (K / 32);
  };
  addw(0, ci_w, WCI, 640, 640, 0);
  addw(1, qkv_w, WQKV, 640, 1920, 0);
  addw(2, saw_w, WSAW, 640, 640, 0);
  addw(3, caq_w, WCAQ, 640, 640, 0);
  addw(4, cak_w, WCAKV, 512, 640, 0);
  addw(5, cav_w, WCAKV + (size_t)640 * 512, 512, 640, 0);
  addw(6, caw_w, WCAW, 640, 640, 0);
  addw(7, g1_w, WG1, 640, 5120, 1);  // GEGLU interleave
  addw(8, g2_w, WG2, 2560, 640, 0);
  addw(9, co_w, WCO, 640, 640, 0);
  prep_all<<<boff, 256, 0, stream>>>(pa);
  // prompt conv + bias concat + gn_stats in one dispatch
  misc_prep<<<1493, 256, 0, stream>>>(p, PBF, cak_b, cav_b, CBIAS, x, GNM, GNR);

  // ---- groupnorm apply ----
  gn_apply<<<dim3(32, 20, 8), 256, 0, stream>>>(x, GNM, GNR, gn_g, gn_b, X);

  const float scale = 0.11180339887498949f;  // 1/sqrt(80)

  // conv_input -> bf16 residual stream
  gemm_bt64<1><<<dim3(128, 5), 256, 0, stream>>>(X, WCI, ci_b, F1B, nullptr, 8192, 640, 640);
  // self-attention
  ln_kernel<<<2048, 256, 0, stream>>>(F1B, ln1_g, ln1_b, Y);
  gemm256<1><<<dim3(32, 8), 512, 0, stream>>>(Y, WQKV, qkv_b, QKV, nullptr, 8192, 1920, 640);
  attn_kernel<<<dim3(8, 8, 8), 512, 0, stream>>>(QKV, 1920, (long)1024 * 1920,
                                                 QKV + 640, 1920, (long)1024 * 1920,
                                                 QKV + 1280, X, 640, (long)1024 * 640,
                                                 1024, scale);
  gemm_bt64<6><<<dim3(128, 5), 256, 0, stream>>>(X, WSAW, saw_b, F1B, (const float*)F1B,
                                                 8192, 640, 640);
  // cross-attention: caq (640 blocks) + KV projection (100 blocks) in ONE dispatch
  ln_kernel<<<2048, 256, 0, stream>>>(F1B, ln2_g, ln2_b, Y);
  gemm_bt64_dual<1, 1><<<740, 256, 0, stream>>>(
      Y, WCAQ, caq_b, X, 8192, 640, 640, 128, 5,
      PBF, WCAKV, CBIAS, KVC, 616, 1280, 512, 10, 10,
      640);
  attn_kernel<<<dim3(8, 8, 8), 512, 0, stream>>>(X, 640, (long)1024 * 640,
                                                 KVC, 1280, (long)77 * 1280,
                                                 KVC + 640, Y, 640, (long)1024 * 640,
                                                 77, scale);
  gemm_bt64<6><<<dim3(128, 5), 256, 0, stream>>>(Y, WCAW, caw_b, F1B, (const float*)F1B,
                                                 8192, 640, 640);
  // GEGLU MLP: g1 with fused GEGLU epilogue -> TG
  ln_kernel<<<2048, 256, 0, stream>>>(F1B, ln3_g, ln3_b, X);
  gemm256<5><<<dim3(32, 20), 512, 0, stream>>>(X, WG1, g1_b, TG, nullptr, 8192, 5120, 640);
  gemm_bt64<6><<<dim3(128, 5), 256, 0, stream>>>(TG, WG2, g2_b, X, (const float*)F1B,
                                                 8192, 640, 2560);
  // conv_output + long residual (transposed store)
  gemm_bt64<3><<<dim3(128, 5), 256, 0, stream>>>(X, WCO, co_b, out, x, 8192, 640, 640);
}

// Round 22
// 404.547 us; speedup vs baseline: 1.0286x; 1.0286x over previous
//
#include <hip/hip_runtime.h>
#include <math.h>

typedef unsigned short u16;
typedef __attribute__((ext_vector_type(8))) short short8;
typedef __attribute__((ext_vector_type(4))) float f32x4;

#define DI static __device__ __forceinline__

DI float bf2f(u16 u) { union { unsigned u; float f; } c; c.u = (unsigned)u << 16; return c.f; }
DI u16 f2bf(float f) {
  union { float f; unsigned u; } c; c.f = f;
  unsigned r = c.u + 0x7fffu + ((c.u >> 16) & 1u);
  return (u16)(r >> 16);
}

// async global->LDS, 16 bytes per lane; dest MUST be wave-linear (base + lane*16)
DI void gload16(const u16* g, u16* l) {
  __builtin_amdgcn_global_load_lds(
      (const __attribute__((address_space(1))) unsigned int*)g,
      (__attribute__((address_space(3))) unsigned int*)l, 16, 0, 0);
}

// bijective XCD-aware block swizzle (m204 form) -- fallback
DI void xcd_swz(int& bx, int& by, int gx, int gy) {
  int id = by * gx + bx;
  int n = gx * gy;
  int q = n >> 3, r = n & 7;
  int xcd = id & 7, k = id >> 3;
  int s = (xcd < r) ? (xcd * (q + 1) + k) : (r * (q + 1) + (xcd - r) * q + k);
  bx = s % gx;
  by = s / gx;
}

// rectangular XCD chunking (for gemm256 grids): each XCD owns an 8 x RH rect
// so its working set fits the 4MB per-XCD L2 (round-13: g1 FETCH 108->43MB).
DI void xcd_swz_rect(int& bx, int& by, int gx, int gy) {
  if ((gx & 7) == 0) {
    int RC = gx >> 3;
    if (RC <= 8 && (8 % RC) == 0) {
      int RR = 8 / RC;
      if ((gy % RR) == 0) {
        int id = by * gx + bx;
        int xcd = id & 7, k = id >> 3;
        int rc = xcd % RC, rr = xcd / RC;
        int RH = gy / RR;
        bx = rc * 8 + (k & 7);
        by = rr * RH + (k >> 3);
        return;
      }
    }
  }
  xcd_swz(bx, by, gx, gy);
}

// fragment read with XOR swizzle
DI const short8* fragp(const u16* unit, int row, int g4) {
  int off = row * 64 + g4 * 16;
  off ^= ((off >> 7) & 3) << 4;
  return (const short8*)((const char*)unit + off);
}

// ---------- merged weight prep: 10 transposes in one dispatch ----------
struct PrepDesc { const float* src; u16* dst; int K, N, nbx, boff, perm; };
struct PrepArgs { PrepDesc d[10]; };

__global__ __launch_bounds__(256) void prep_all(PrepArgs a) {
  int bid = blockIdx.x;
  int i = 0;
  while (i < 9 && bid >= a.d[i + 1].boff) i++;
  const PrepDesc D = a.d[i];
  int rel = bid - D.boff;
  int bx = rel % D.nbx, by = rel / D.nbx;
  int K = D.K, N = D.N;
  __shared__ float tile[32][33];
  int k0 = by * 32, n0 = bx * 32;
  int tid = threadIdx.x;
  int ni = tid & 31, ki8 = tid >> 5;
  for (int q = 0; q < 4; q++) {
    int k = ki8 + q * 8;
    tile[k][ni] = D.src[(size_t)(k0 + k) * N + n0 + ni];
  }
  __syncthreads();
  int kj = tid & 31, nj8 = tid >> 5;
  for (int q = 0; q < 4; q++) {
    int n = nj8 + q * 8;
    int nold = n0 + n;
    int rowp = nold;
    if (D.perm) {
      rowp = (nold < 2560) ? ((nold >> 5) * 64 + (nold & 31))
                           : (((nold - 2560) >> 5) * 64 + 32 + (nold & 31));
    }
    D.dst[(size_t)rowp * K + k0 + kj] = f2bf(tile[kj][n]);
  }
}

// ---------- misc prep: prompt f32->bf16 (0..1231) + bias concat (1232..1236)
//            + GroupNorm stats (1237..1492) ----------
__global__ __launch_bounds__(256) void misc_prep(const float* __restrict__ p,
                                                 u16* __restrict__ pbf,
                                                 const float* __restrict__ ka,
                                                 const float* __restrict__ va,
                                                 float* __restrict__ cbias,
                                                 const float* __restrict__ x,
                                                 float* __restrict__ mean_o,
                                                 float* __restrict__ rstd_o) {
  int bid = blockIdx.x;
  if (bid < 1232) {
    long i = (long)bid * 256 + threadIdx.x;
    if (i < (long)616 * 512) pbf[i] = f2bf(p[i]);
  } else if (bid < 1237) {
    int i = (bid - 1232) * 256 + threadIdx.x;
    if (i < 640) cbias[i] = ka[i];
    else if (i < 1280) cbias[i] = va[i - 640];
  } else {
    int bg = bid - 1237;
    const float4* p4 = (const float4*)(x + (size_t)bg * 20480);
    float s = 0.f, sq = 0.f;
    for (int i = threadIdx.x; i < 5120; i += 256) {
      float4 v = p4[i];
      s += v.x + v.y + v.z + v.w;
      sq += v.x * v.x + v.y * v.y + v.z * v.z + v.w * v.w;
    }
    for (int off = 1; off < 64; off <<= 1) { s += __shfl_xor(s, off); sq += __shfl_xor(sq, off); }
    __shared__ float ps[4], pq[4];
    int w = threadIdx.x >> 6;
    if ((threadIdx.x & 63) == 0) { ps[w] = s; pq[w] = sq; }
    __syncthreads();
    if (threadIdx.x == 0) {
      float S = ps[0] + ps[1] + ps[2] + ps[3];
      float Q = pq[0] + pq[1] + pq[2] + pq[3];
      float mu = S / 20480.f;
      float var = Q / 20480.f - mu * mu;
      mean_o[bg] = mu;
      rstd_o[bg] = rsqrtf(var + 1e-5f);
    }
  }
}

// ---------- GN apply + transpose ----------
__global__ __launch_bounds__(256) void gn_apply(const float* __restrict__ x,
                                                const float* __restrict__ mean_,
                                                const float* __restrict__ rstd_,
                                                const float* __restrict__ g,
                                                const float* __restrict__ bb,
                                                u16* __restrict__ out) {
  __shared__ float tile[32][33];
  int b = blockIdx.z, c0 = blockIdx.y * 32, s0 = blockIdx.x * 32;
  int tid = threadIdx.x;
  int si = tid & 31, ci8 = tid >> 5;
  for (int i = 0; i < 4; i++) {
    int c = c0 + ci8 + i * 8;
    int gg = c / 20;
    float mu = mean_[b * 32 + gg], rs = rstd_[b * 32 + gg];
    float v = x[((size_t)b * 640 + c) * 1024 + s0 + si];
    tile[ci8 + i * 8][si] = (v - mu) * rs * g[c] + bb[c];
  }
  __syncthreads();
  int cj = tid & 31, sj8 = tid >> 5;
  for (int i = 0; i < 4; i++) {
    int sj = sj8 + i * 8;
    out[((size_t)b * 1024 + s0 + sj) * 640 + c0 + cj] = f2bf(tile[cj][sj]);
  }
}

// ---------- LayerNorm: bf16 [T,640] -> bf16 [T,640], vectorized short8 loads ----------
__global__ __launch_bounds__(256) void ln_kernel(const u16* __restrict__ in,
                                                 const float* __restrict__ g,
                                                 const float* __restrict__ bb,
                                                 u16* __restrict__ out) {
  int t = blockIdx.x * 4 + (threadIdx.x >> 6);
  int lane = threadIdx.x & 63;
  const u16* row = in + (size_t)t * 640;
  const bool tail = (lane < 16);
  short8 v0 = *(const short8*)(row + lane * 8);
  short8 v1 = tail ? *(const short8*)(row + 512 + lane * 8) : short8{0,0,0,0,0,0,0,0};
  float f0[8], f1[8];
  float s = 0.f, sq = 0.f;
#pragma unroll
  for (int e = 0; e < 8; e++) {
    f0[e] = bf2f((u16)v0[e]);
    s += f0[e];
    sq += f0[e] * f0[e];
  }
  if (tail) {
#pragma unroll
    for (int e = 0; e < 8; e++) {
      f1[e] = bf2f((u16)v1[e]);
      s += f1[e];
      sq += f1[e] * f1[e];
    }
  }
#pragma unroll
  for (int off = 1; off < 64; off <<= 1) { s += __shfl_xor(s, off); sq += __shfl_xor(sq, off); }
  float mu = s * (1.f / 640.f);
  float var = sq * (1.f / 640.f) - mu * mu;
  float rstd = rsqrtf(var + 1e-5f);
  short8 o0;
#pragma unroll
  for (int e = 0; e < 8; e++) {
    int c = lane * 8 + e;
    o0[e] = (short)f2bf((f0[e] - mu) * rstd * g[c] + bb[c]);
  }
  *(short8*)(out + (size_t)t * 640 + lane * 8) = o0;
  if (tail) {
    short8 o1;
#pragma unroll
    for (int e = 0; e < 8; e++) {
      int c = 512 + lane * 8 + e;
      o1[e] = (short)f2bf((f1[e] - mu) * rstd * g[c] + bb[c]);
    }
    *(short8*)(out + (size_t)t * 640 + 512 + lane * 8) = o1;
  }
}

// ---------- epilogue helper ----------
// MODE 1: bf16 = acc+bias    MODE 6: bf16 = acc+bias+bf16res
template <int MODE>
DI void store_elem(void* outp, const float* res, size_t o, float val) {
  if (MODE == 1)
    ((u16*)outp)[o] = f2bf(val);
  else if (MODE == 6)
    ((u16*)outp)[o] = f2bf(val + bf2f(((const u16*)res)[o]));
}

// ================= 256x256 fine-phased GEMM (g1, qkv) =================
template <int MODE>
__global__ __launch_bounds__(512, 1) void gemm256(const u16* __restrict__ A,
                                                  const u16* __restrict__ Bt,
                                                  const float* __restrict__ bias,
                                                  void* outp, const float* res,
                                                  int M, int N, int K) {
  __shared__ __align__(16) u16 As[4][8192];
  __shared__ __align__(16) u16 Bs[4][8192];
  const int tid = threadIdx.x;
  const int lane = tid & 63, wid = tid >> 6;
  const int wm = wid >> 2, wn = wid & 3;
  const int rq = lane & 15, g4 = lane >> 4;
  int bx = blockIdx.x, by = blockIdx.y;
  xcd_swz_rect(bx, by, gridDim.x, gridDim.y);
  const int m0 = bx * 256, n0 = by * 256;

  int D0 = tid * 16;
  int so = D0 ^ (((D0 >> 7) & 3) << 4);
  const int srow = so >> 6;
  const int sk16 = (so & 63) >> 1;

  f32x4 acc[8][4] = {};
  const int nt = K >> 5;

#define STG_A(kt)                                                              \
  {                                                                            \
    gload16(A + (size_t)(m0 + srow) * K + (kt)*32 + sk16,                      \
            &As[(kt) & 3][0] + tid * 8);                                       \
    gload16(A + (size_t)(m0 + 128 + srow) * K + (kt)*32 + sk16,                \
            &As[(kt) & 3][4096] + tid * 8);                                    \
  }
#define STG_B(kt)                                                              \
  {                                                                            \
    gload16(Bt + (size_t)(n0 + srow) * K + (kt)*32 + sk16,                     \
            &Bs[(kt) & 3][0] + tid * 8);                                       \
    gload16(Bt + (size_t)(n0 + 128 + srow) * K + (kt)*32 + sk16,               \
            &Bs[(kt) & 3][4096] + tid * 8);                                    \
  }
#define BAR asm volatile("s_barrier" ::: "memory")

#define PH1(T)                                                                 \
  {                                                                            \
    const u16* Au = &As[(T) & 3][0];                                           \
    const u16* Bu = &Bs[(T) & 3][0];                                           \
    _Pragma("unroll") for (int i = 0; i < 4; i++)                              \
        af[i] = *fragp(Au, wm * 128 + i * 16 + rq, g4);                        \
    _Pragma("unroll") for (int j = 0; j < 4; j++)                              \
        bf[j] = *fragp(Bu, wn * 64 + j * 16 + rq, g4);                         \
    BAR;                                                                       \
    asm volatile("s_waitcnt lgkmcnt(0)" ::: "memory");                         \
    __builtin_amdgcn_sched_barrier(0);                                         \
    __builtin_amdgcn_s_setprio(1);                                             \
    _Pragma("unroll") for (int i = 0; i < 4; i++)                              \
        _Pragma("unroll") for (int j = 0; j < 4; j++)                          \
            acc[i][j] =                                                        \
        __builtin_amdgcn_mfma_f32_16x16x32_bf16(af[i], bf[j], acc[i][j], 0, 0, 0); \
    __builtin_amdgcn_s_setprio(0);                                             \
  }

#define PH2(T, DO_STG, WSTR)                                                   \
  {                                                                            \
    const u16* Au = &As[(T) & 3][0];                                           \
    _Pragma("unroll") for (int i = 0; i < 4; i++)                              \
        af[i] = *fragp(Au, wm * 128 + 64 + i * 16 + rq, g4);                   \
    if (DO_STG) { STG_A((T) + 3); STG_B((T) + 3); }                            \
    asm volatile(WSTR ::: "memory");                                           \
    BAR;                                                                       \
    asm volatile("s_waitcnt lgkmcnt(0)" ::: "memory");                         \
    __builtin_amdgcn_sched_barrier(0);                                         \
    __builtin_amdgcn_s_setprio(1);                                             \
    _Pragma("unroll") for (int i = 0; i < 4; i++)                              \
        _Pragma("unroll") for (int j = 0; j < 4; j++)                          \
            acc[4 + i][j] =                                                    \
        __builtin_amdgcn_mfma_f32_16x16x32_bf16(af[i], bf[j], acc[4 + i][j], 0, 0, 0); \
    __builtin_amdgcn_s_setprio(0);                                             \
  }

  STG_A(0); STG_B(0); STG_A(1); STG_B(1); STG_A(2); STG_B(2);
  asm volatile("s_waitcnt vmcnt(8)" ::: "memory");
  BAR;

  short8 af[4], bf[4];
  int t = 0;
  for (; t < nt - 3; t++) {
    PH1(t);
    PH2(t, true, "s_waitcnt vmcnt(8)");
  }
  PH1(t); PH2(t, false, "s_waitcnt vmcnt(4)"); t++;
  PH1(t); PH2(t, false, "s_waitcnt vmcnt(0)"); t++;
  PH1(t); PH2(t, false, "s_nop 0");

  if (MODE == 5) {
#pragma unroll
    for (int mf = 0; mf < 8; mf++) {
      int mb = m0 + wm * 128 + mf * 16 + g4 * 4;
#pragma unroll
      for (int j = 0; j < 2; j++) {
        int n = n0 + wn * 64 + j * 16 + rq;  // (n&63) < 32
        int c = (n >> 6) * 32 + (n & 31);
        float ba = bias[c];
        float bg = bias[2560 + c];
#pragma unroll
        for (int r = 0; r < 4; r++) {
          float a = acc[mf][j][r] + ba;
          float gt = acc[mf][j + 2][r] + bg;
          float gl = 0.5f * gt * (1.f + erff(gt * 0.70710678f));
          ((u16*)outp)[(size_t)(mb + r) * 2560 + c] = f2bf(a * gl);
        }
      }
    }
  } else {
#pragma unroll
    for (int mf = 0; mf < 8; mf++) {
#pragma unroll
      for (int j = 0; j < 4; j++) {
        int n = n0 + wn * 64 + j * 16 + rq;
        if (n >= N) continue;
        float bv = bias[n];
        int mb = m0 + wm * 128 + mf * 16 + g4 * 4;
        f32x4 v = acc[mf][j];
#pragma unroll
        for (int r = 0; r < 4; r++) {
          size_t o = (size_t)(mb + r) * N + n;
          ((u16*)outp)[o] = f2bf(v[r] + bv);
        }
      }
    }
  }
  (void)res;
#undef STG_A
#undef STG_B
#undef PH1
#undef PH2
#undef BAR
}

// ========= 64x128 GEMM body (shared by single & dual kernels) =========
// MODE 1: bf16  MODE 3: NCHW fp32 + x residual  MODE 6: bf16 = acc+bias+bf16res
template <int MODE>
DI void gemm64_body(u16* AsB, u16* BsB,
                    const u16* __restrict__ A, const u16* __restrict__ Bt,
                    const float* __restrict__ bias, void* outp, const float* res,
                    int M, int N, int K, int bx, int by, int gx, int gy) {
  const int tid = threadIdx.x;
  const int lane = tid & 63, wid = tid >> 6;
  const int wm = wid >> 1, wn = wid & 1;
  xcd_swz(bx, by, gx, gy);
  const int m0 = bx * 64, n0 = by * 128;
  const int rq = lane & 15, g4 = lane >> 4;

  int D0 = tid * 16;
  int so = D0 ^ (((D0 >> 7) & 3) << 4);
  const int srowS = so >> 6;
  const int sk16 = (so & 63) >> 1;
  int gmA = m0 + srowS;  if (gmA >= M) gmA = M - 1;
  const u16* gA = A + (size_t)gmA * K + sk16;
  const u16* gB0 = Bt + (size_t)(n0 + srowS) * K + sk16;
  const u16* gB1 = Bt + (size_t)(n0 + 64 + srowS) * K + sk16;

  f32x4 acc[2][4] = {};

  auto STAGE = [&](int buf, int k0) {
    gload16(gA + k0, AsB + buf * 2048 + tid * 8);
    gload16(gB0 + k0, BsB + buf * 4096 + tid * 8);
    gload16(gB1 + k0, BsB + buf * 4096 + 2048 + tid * 8);
  };
  auto COMPUTE = [&](int buf) {
    short8 af[2], bfr[4];
    for (int i = 0; i < 2; i++)
      af[i] = *fragp(AsB + buf * 2048, wm * 32 + i * 16 + rq, g4);
    for (int j = 0; j < 4; j++)
      bfr[j] = *fragp(BsB + buf * 4096, wn * 64 + j * 16 + rq, g4);
    __builtin_amdgcn_s_setprio(1);
    for (int i = 0; i < 2; i++)
      for (int j = 0; j < 4; j++)
        acc[i][j] = __builtin_amdgcn_mfma_f32_16x16x32_bf16(af[i], bfr[j], acc[i][j], 0, 0, 0);
    __builtin_amdgcn_s_setprio(0);
  };

  const int nk = K >> 5;
  STAGE(0, 0);
  STAGE(1, 32);
  int t = 0;
  for (; t < nk - 2; t++) {
    STAGE((t + 2) & 3, (t + 2) << 5);
    asm volatile("s_waitcnt vmcnt(6)" ::: "memory");
    __builtin_amdgcn_s_barrier();
    COMPUTE(t & 3);
  }
  asm volatile("s_waitcnt vmcnt(3)" ::: "memory");
  __builtin_amdgcn_s_barrier();
  COMPUTE(t & 3);
  t++;
  asm volatile("s_waitcnt vmcnt(0)" ::: "memory");
  __builtin_amdgcn_s_barrier();
  COMPUTE(t & 3);

  for (int j = 0; j < 4; j++) {
    int n = n0 + wn * 64 + j * 16 + rq;
    float bv = bias[n];
    for (int i = 0; i < 2; i++) {
      int mb = m0 + wm * 32 + i * 16 + g4 * 4;
      f32x4 v = acc[i][j];
      if (MODE == 3) {
        int b = mb >> 10, sp = mb & 1023;
        size_t o = ((size_t)b * 640 + n) * 1024 + sp;
        f32x4 xv = *(const f32x4*)(res + o);
        f32x4 ov;
        for (int r = 0; r < 4; r++) ov[r] = v[r] + bv + xv[r];
        *(f32x4*)((float*)outp + o) = ov;
      } else {
        for (int r = 0; r < 4; r++) {
          int m = mb + r;
          if (m >= M) break;
          store_elem<MODE>(outp, res, (size_t)m * N + n, v[r] + bv);
        }
      }
    }
  }
}

template <int MODE>
__global__ __launch_bounds__(256) void gemm_bt64(const u16* __restrict__ A,
                                                 const u16* __restrict__ Bt,
                                                 const float* __restrict__ bias,
                                                 void* outp, const float* res,
                                                 int M, int N, int K) {
  __shared__ __align__(16) u16 As[4 * 2048];
  __shared__ __align__(16) u16 Bs[4 * 4096];
  gemm64_body<MODE>(As, Bs, A, Bt, bias, outp, res, M, N, K,
                    blockIdx.x, blockIdx.y, gridDim.x, gridDim.y);
}

// dual-problem launch: blocks [0, nb1) run problem 1, rest run problem 2.
template <int MODE1, int MODE2>
__global__ __launch_bounds__(256) void gemm_bt64_dual(
    const u16* A1, const u16* Bt1, const float* b1, void* o1, int M1, int N1, int K1, int gx1, int gy1,
    const u16* A2, const u16* Bt2, const float* b2, void* o2, int M2, int N2, int K2, int gx2, int gy2,
    int nb1) {
  __shared__ __align__(16) u16 As[4 * 2048];
  __shared__ __align__(16) u16 Bs[4 * 4096];
  int id = blockIdx.x;
  if (id < nb1) {
    gemm64_body<MODE1>(As, Bs, A1, Bt1, b1, o1, nullptr, M1, N1, K1,
                       id % gx1, id / gx1, gx1, gy1);
  } else {
    id -= nb1;
    gemm64_body<MODE2>(As, Bs, A2, Bt2, b2, o2, nullptr, M2, N2, K2,
                       id % gx2, id / gx2, gx2, gy2);
  }
}

// ---------- flash attention: swapped QK^T, in-lane softmax, 16 q/wave, 8 waves ----------
// K-tile prefetched into registers one iteration ahead (T14 async-STAGE split):
// loads issued right after the staging barrier land under QK^T/softmax/PV compute.
// (V staged inline -- round-21 V-prefetch regressed: VGPR cliff + serialized WRITEV.)
__global__ __launch_bounds__(512) void attn_kernel(const u16* __restrict__ Qb, int ldq, long qbs,
                                                   const u16* __restrict__ Kb, int ldk, long kbs,
                                                   const u16* __restrict__ Vb,
                                                   u16* __restrict__ Ob, int ldo, long obs,
                                                   int Sk, float scale) {
  __shared__ __align__(16) u16 Ks[64 * 96];
  __shared__ __align__(16) u16 Vt[80 * 64];
  __shared__ __align__(16) u16 Ps[8][16 * 72];
  const short8 zero = {0, 0, 0, 0, 0, 0, 0, 0};
  const int tid = threadIdx.x;
  const int lane = tid & 63, w = tid >> 6;
  const int rq = lane & 15, g4 = lane >> 4;
  const int b = blockIdx.z, h = blockIdx.y;
  const u16* Q = Qb + (size_t)b * qbs + h * 80;
  const u16* Kp = Kb + (size_t)b * kbs + h * 80;
  const u16* Vp = Vb + (size_t)b * kbs + h * 80;
  u16* Op = Ob + (size_t)b * obs + h * 80;
  const int q0 = blockIdx.x * 128 + w * 16;
  const float Af = scale * 1.44269504f;

  short8 qa[3];
#pragma unroll
  for (int kk = 0; kk < 3; kk++) {
    int d = kk * 32 + g4 * 8;
    qa[kk] = (d < 80) ? *(const short8*)(Q + (size_t)(q0 + rq) * ldq + d) : zero;
  }
  f32x4 oacc[5] = {};
  float m_run = -1e30f, l_run = 0.f;

  // K-prefetch registers: chunk s=tid (row=s/12,c=s%12) and s=tid+512 (tid<256)
  const int r0 = tid / 12, c0_ = tid % 12;
  const int s1 = tid + 512;
  const int r1 = s1 / 12, c1_ = s1 % 12;
  short8 kr0, kr1;
  auto LOADK = [&](int kt) {
    int kb0 = kt * 64 + r0;
    kr0 = (c0_ < 10 && kb0 < Sk) ? *(const short8*)(Kp + (size_t)kb0 * ldk + c0_ * 8) : zero;
    if (tid < 256) {
      int kb1 = kt * 64 + r1;
      kr1 = (c1_ < 10 && kb1 < Sk) ? *(const short8*)(Kp + (size_t)kb1 * ldk + c1_ * 8) : zero;
    }
  };
  auto WRITEK = [&]() {
    int byte0 = r0 * 192 + c0_ * 16;
    byte0 ^= (r0 & 7) << 4;
    *(short8*)((char*)Ks + byte0) = kr0;
    if (tid < 256) {
      int byte1 = r1 * 192 + c1_ * 16;
      byte1 ^= (r1 & 7) << 4;
      *(short8*)((char*)Ks + byte1) = kr1;
    }
  };

  const int nkt = (Sk + 63) >> 6;
  LOADK(0);
  for (int kt = 0; kt < nkt; kt++) {
    const int kbase = kt * 64;
    WRITEK();  // compiler waits on kr loads here
    for (int s = tid; s < 320; s += 512) {
      int k2 = (s & 31) * 2, c = s >> 5;
      int k0i = kbase + k2;
      short8 v0 = zero, v1 = zero;
      if (k0i < Sk) v0 = *(const short8*)(Vp + (size_t)k0i * ldk + c * 8);
      if (k0i + 1 < Sk) v1 = *(const short8*)(Vp + (size_t)(k0i + 1) * ldk + c * 8);
#pragma unroll
      for (int jj = 0; jj < 8; jj++) {
        int d = c * 8 + jj;
        unsigned cm = (unsigned)(u16)v0[jj] | ((unsigned)(u16)v1[jj] << 16);
        int byte = d * 128 + k2 * 2;
        byte ^= (d & 7) << 4;
        *(unsigned*)((char*)Vt + byte) = cm;
      }
    }
    __syncthreads();
    if (kt + 1 < nkt) LOADK(kt + 1);  // lands under compute below

    f32x4 sc[4] = {};
#pragma unroll
    for (int n = 0; n < 4; n++)
#pragma unroll
      for (int kk = 0; kk < 3; kk++) {
        int row = n * 16 + rq;
        int byte = row * 192 + (kk * 32 + g4 * 8) * 2;
        byte ^= (rq & 7) << 4;
        short8 kb = *(const short8*)((const char*)Ks + byte);
        sc[n] = __builtin_amdgcn_mfma_f32_16x16x32_bf16(kb, qa[kk], sc[n], 0, 0, 0);
      }
    const bool full = (kbase + 64 <= Sk);
    if (!full) {
#pragma unroll
      for (int n = 0; n < 4; n++)
#pragma unroll
        for (int r = 0; r < 4; r++)
          if (kbase + n * 16 + g4 * 4 + r >= Sk) sc[n][r] = -1e30f;
    }
    float t0 = fmaxf(fmaxf(sc[0][0], sc[0][1]), fmaxf(sc[0][2], sc[0][3]));
    float t1 = fmaxf(fmaxf(sc[1][0], sc[1][1]), fmaxf(sc[1][2], sc[1][3]));
    float t2 = fmaxf(fmaxf(sc[2][0], sc[2][1]), fmaxf(sc[2][2], sc[2][3]));
    float t3 = fmaxf(fmaxf(sc[3][0], sc[3][1]), fmaxf(sc[3][2], sc[3][3]));
    float tm = fmaxf(fmaxf(t0, t1), fmaxf(t2, t3));
    tm = fmaxf(tm, __shfl_xor(tm, 16));
    tm = fmaxf(tm, __shfl_xor(tm, 32));
    if (!__all(tm <= m_run + 48.0f)) {
      float mn = fmaxf(m_run, tm);
      float sf = exp2f(Af * (m_run - mn));
      m_run = mn;
      l_run *= sf;
      float sfo[4];
#pragma unroll
      for (int r = 0; r < 4; r++) sfo[r] = __shfl(sf, g4 * 4 + r);
#pragma unroll
      for (int nn = 0; nn < 5; nn++)
#pragma unroll
        for (int r = 0; r < 4; r++) oacc[nn][r] *= sfo[r];
    }
    const float Am = Af * m_run;
    float rs0 = 0.f, rs1 = 0.f;
#pragma unroll
    for (int n = 0; n < 4; n++) {
      float p0 = exp2f(fmaf(Af, sc[n][0], -Am));
      float p1 = exp2f(fmaf(Af, sc[n][1], -Am));
      float p2 = exp2f(fmaf(Af, sc[n][2], -Am));
      float p3 = exp2f(fmaf(Af, sc[n][3], -Am));
      sc[n][0] = p0; sc[n][1] = p1; sc[n][2] = p2; sc[n][3] = p3;
      rs0 += p0 + p1;
      rs1 += p2 + p3;
    }
    float rsum = rs0 + rs1;
    rsum += __shfl_xor(rsum, 16);
    rsum += __shfl_xor(rsum, 32);
    l_run += rsum;
#pragma unroll
    for (int n = 0; n < 4; n++) {
      unsigned pk0, pk1;
      asm("v_cvt_pk_bf16_f32 %0, %1, %2" : "=v"(pk0) : "v"(sc[n][0]), "v"(sc[n][1]));
      asm("v_cvt_pk_bf16_f32 %0, %1, %2" : "=v"(pk1) : "v"(sc[n][2]), "v"(sc[n][3]));
      int base = rq * 72 + n * 16 + g4 * 4;
      *(unsigned*)&Ps[w][base] = pk0;
      *(unsigned*)&Ps[w][base + 2] = pk1;
    }
    __builtin_amdgcn_s_setprio(1);
#pragma unroll
    for (int s = 0; s < 2; s++) {
      short8 pa = *(const short8*)&Ps[w][rq * 72 + s * 32 + g4 * 8];
#pragma unroll
      for (int nn = 0; nn < 5; nn++) {
        int row = nn * 16 + rq;
        int byte = row * 128 + (s * 32 + g4 * 8) * 2;
        byte ^= (rq & 7) << 4;
        short8 vb = *(const short8*)((const char*)Vt + byte);
        oacc[nn] = __builtin_amdgcn_mfma_f32_16x16x32_bf16(pa, vb, oacc[nn], 0, 0, 0);
      }
    }
    __builtin_amdgcn_s_setprio(0);
    __syncthreads();
  }
  float lo[4];
#pragma unroll
  for (int r = 0; r < 4; r++) lo[r] = 1.0f / __shfl(l_run, g4 * 4 + r);
#pragma unroll
  for (int nn = 0; nn < 5; nn++)
#pragma unroll
    for (int r = 0; r < 4; r++)
      Op[(size_t)(q0 + g4 * 4 + r) * ldo + nn * 16 + rq] = f2bf(oacc[nn][r] * lo[r]);
}

extern "C" void kernel_launch(void* const* d_in, const int* in_sizes, int n_in,
                              void* d_out, int out_size, void* d_ws, size_t ws_size,
                              hipStream_t stream) {
  (void)in_sizes; (void)n_in; (void)out_size; (void)ws_size;
  const float* x = (const float*)d_in[0];
  const float* p = (const float*)d_in[1];
  const float* gn_g = (const float*)d_in[2];
  const float* gn_b = (const float*)d_in[3];
  const float* ci_w = (const float*)d_in[4];
  const float* ci_b = (const float*)d_in[5];
  const float* ln1_g = (const float*)d_in[6];
  const float* ln1_b = (const float*)d_in[7];
  const float* qkv_w = (const float*)d_in[8];
  const float* qkv_b = (const float*)d_in[9];
  const float* saw_w = (const float*)d_in[10];
  const float* saw_b = (const float*)d_in[11];
  const float* ln2_g = (const float*)d_in[12];
  const float* ln2_b = (const float*)d_in[13];
  const float* caq_w = (const float*)d_in[14];
  const float* caq_b = (const float*)d_in[15];
  const float* cak_w = (const float*)d_in[16];
  const float* cak_b = (const float*)d_in[17];
  const float* cav_w = (const float*)d_in[18];
  const float* cav_b = (const float*)d_in[19];
  const float* caw_w = (const float*)d_in[20];
  const float* caw_b = (const float*)d_in[21];
  const float* ln3_g = (const float*)d_in[22];
  const float* ln3_b = (const float*)d_in[23];
  const float* g1_w = (const float*)d_in[24];
  const float* g1_b = (const float*)d_in[25];
  const float* g2_w = (const float*)d_in[26];
  const float* g2_b = (const float*)d_in[27];
  const float* co_w = (const float*)d_in[28];
  const float* co_b = (const float*)d_in[29];
  float* out = (float*)d_out;

  char* ws = (char*)d_ws;
  size_t off = 0;
  auto alloc = [&](size_t bytes) {
    size_t o = off;
    off += (bytes + 255) & ~(size_t)255;
    return o;
  };
  u16* WCI = (u16*)(ws + alloc((size_t)768 * 640 * 2));
  u16* WQKV = (u16*)(ws + alloc((size_t)2048 * 640 * 2));
  u16* WSAW = (u16*)(ws + alloc((size_t)768 * 640 * 2));
  u16* WCAQ = (u16*)(ws + alloc((size_t)768 * 640 * 2));
  u16* WCAKV = (u16*)(ws + alloc((size_t)1280 * 512 * 2));
  u16* WCAW = (u16*)(ws + alloc((size_t)768 * 640 * 2));
  u16* WG1 = (u16*)(ws + alloc((size_t)5120 * 640 * 2));
  u16* WG2 = (u16*)(ws + alloc((size_t)768 * 2560 * 2));
  u16* WCO = (u16*)(ws + alloc((size_t)768 * 640 * 2));
  u16* X = (u16*)(ws + alloc((size_t)8192 * 640 * 2));
  u16* Y = (u16*)(ws + alloc((size_t)8192 * 640 * 2));
  u16* F1B = (u16*)(ws + alloc((size_t)8192 * 640 * 2));  // bf16 residual stream
  u16* QKV = (u16*)(ws + alloc((size_t)8192 * 1920 * 2));
  u16* PBF = (u16*)(ws + alloc((size_t)616 * 512 * 2));
  u16* KVC = (u16*)(ws + alloc((size_t)616 * 1280 * 2));
  u16* TG = (u16*)(ws + alloc((size_t)8192 * 2560 * 2));
  float* GNM = (float*)(ws + alloc(256 * 4));
  float* GNR = (float*)(ws + alloc(256 * 4));
  float* CBIAS = (float*)(ws + alloc(1280 * 4));

  // ---- merged weight prep ----
  PrepArgs pa;
  int boff = 0;
  auto addw = [&](int idx, const float* src, u16* dst, int K, int N, int perm) {
    pa.d[idx].src = src; pa.d[idx].dst = dst;
    pa.d[idx].K = K; pa.d[idx].N = N;
    pa.d[idx].nbx = N / 32; pa.d[idx].boff = boff; pa.d[idx].perm = perm;
    boff += (N / 32) * (K / 32);
  };
  addw(0, ci_w, WCI, 640, 640, 0);
  addw(1, qkv_w, WQKV, 640, 1920, 0);
  addw(2, saw_w, WSAW, 640, 640, 0);
  addw(3, caq_w, WCAQ, 640, 640, 0);
  addw(4, cak_w, WCAKV, 512, 640, 0);
  addw(5, cav_w, WCAKV + (size_t)640 * 512, 512, 640, 0);
  addw(6, caw_w, WCAW, 640, 640, 0);
  addw(7, g1_w, WG1, 640, 5120, 1);  // GEGLU interleave
  addw(8, g2_w, WG2, 2560, 640, 0);
  addw(9, co_w, WCO, 640, 640, 0);
  prep_all<<<boff, 256, 0, stream>>>(pa);
  // prompt conv + bias concat + gn_stats in one dispatch
  misc_prep<<<1493, 256, 0, stream>>>(p, PBF, cak_b, cav_b, CBIAS, x, GNM, GNR);

  // ---- groupnorm apply ----
  gn_apply<<<dim3(32, 20, 8), 256, 0, stream>>>(x, GNM, GNR, gn_g, gn_b, X);

  const float scale = 0.11180339887498949f;  // 1/sqrt(80)

  // conv_input -> bf16 residual stream
  gemm_bt64<1><<<dim3(128, 5), 256, 0, stream>>>(X, WCI, ci_b, F1B, nullptr, 8192, 640, 640);
  // self-attention
  ln_kernel<<<2048, 256, 0, stream>>>(F1B, ln1_g, ln1_b, Y);
  gemm256<1><<<dim3(32, 8), 512, 0, stream>>>(Y, WQKV, qkv_b, QKV, nullptr, 8192, 1920, 640);
  attn_kernel<<<dim3(8, 8, 8), 512, 0, stream>>>(QKV, 1920, (long)1024 * 1920,
                                                 QKV + 640, 1920, (long)1024 * 1920,
                                                 QKV + 1280, X, 640, (long)1024 * 640,
                                                 1024, scale);
  gemm_bt64<6><<<dim3(128, 5), 256, 0, stream>>>(X, WSAW, saw_b, F1B, (const float*)F1B,
                                                 8192, 640, 640);
  // cross-attention: caq (640 blocks) + KV projection (100 blocks) in ONE dispatch
  ln_kernel<<<2048, 256, 0, stream>>>(F1B, ln2_g, ln2_b, Y);
  gemm_bt64_dual<1, 1><<<740, 256, 0, stream>>>(
      Y, WCAQ, caq_b, X, 8192, 640, 640, 128, 5,
      PBF, WCAKV, CBIAS, KVC, 616, 1280, 512, 10, 10,
      640);
  attn_kernel<<<dim3(8, 8, 8), 512, 0, stream>>>(X, 640, (long)1024 * 640,
                                                 KVC, 1280, (long)77 * 1280,
                                                 KVC + 640, Y, 640, (long)1024 * 640,
                                                 77, scale);
  gemm_bt64<6><<<dim3(128, 5), 256, 0, stream>>>(Y, WCAW, caw_b, F1B, (const float*)F1B,
                                                 8192, 640, 640);
  // GEGLU MLP: g1 with fused GEGLU epilogue -> TG
  ln_kernel<<<2048, 256, 0, stream>>>(F1B, ln3_g, ln3_b, X);
  gemm256<5><<<dim3(32, 20), 512, 0, stream>>>(X, WG1, g1_b, TG, nullptr, 8192, 5120, 640);
  gemm_bt64<6><<<dim3(128, 5), 256, 0, stream>>>(TG, WG2, g2_b, X, (const float*)F1B,
                                                 8192, 640, 2560);
  // conv_output + long residual (transposed store)
  gemm_bt64<3><<<dim3(128, 5), 256, 0, stream>>>(X, WCO, co_b, out, x, 8192, 640, 640);
}